// Round 2
// baseline (920.822 us; speedup 1.0000x reference)
//
#include <hip/hip_runtime.h>
#include <hip/hip_bf16.h>

#define NB 1024
#define NC 1024
#define NE 128
#define NH 8
#define EH 16
#define INFV 1.0e8f
#define TILE 64
#define LSTRIDE 132   // 128 + 4 floats pad: per-wave b128 access puts exactly 8 dwords on every bank

__device__ __forceinline__ float wredmax64(float v) {
#pragma unroll
    for (int m = 32; m >= 1; m >>= 1) v = fmaxf(v, __shfl_xor(v, m, 64));
    return v;
}
__device__ __forceinline__ float wredsum64(float v) {
#pragma unroll
    for (int m = 32; m >= 1; m >>= 1) v += __shfl_xor(v, m, 64);
    return v;
}

__global__ __launch_bounds__(512, 4)
void decoder_mha_fused(const float* __restrict__ h, const float* __restrict__ hN,
                       const float* __restrict__ hprev, const float* __restrict__ h0,
                       const int* __restrict__ mask,
                       const float* __restrict__ Qw, const float* __restrict__ Qb,
                       const float* __restrict__ Vw, const float* __restrict__ Vb,
                       const float* __restrict__ Wow, const float* __restrict__ Wob,
                       const float* __restrict__ Qfw, const float* __restrict__ Qfb,
                       const float* __restrict__ Kfw, const float* __restrict__ Kfb,
                       float* __restrict__ out) {
    __shared__ __align__(16) float hs[TILE * LSTRIDE];   // h tile, padded
    __shared__ __align__(16) float wdot[NH * NE];        // Vw_h^T @ q_h per head
    __shared__ __align__(16) float hc[3 * NE];
    __shared__ __align__(16) float qv[NE];
    __shared__ __align__(16) float hbarn[NH * NE];       // normalized hbar
    __shared__ __align__(16) float ctx[NE];
    __shared__ __align__(16) float dec[NE];
    __shared__ __align__(16) float qfv[NE];
    __shared__ __align__(16) float qk[NE];
    __shared__ __align__(16) float red[NE];
    __shared__ float d0q[NH];
    __shared__ float qb0s;

    const int b = blockIdx.x;
    const int tid = threadIdx.x;
    const int lane = tid & 63;
    const int wid = tid >> 6;          // wave id == head id in pass 1
    const int hl = lane & 31;
    const int hi = lane >> 5;

    const float* hb = h + (size_t)b * NC * NE;

    // ---------------- phase 0: q, w_dot, d0 ----------------
    if (tid < 128)      hc[tid] = hN[b * NE + tid];
    else if (tid < 256) hc[tid] = hprev[b * NE + (tid - 128)];
    else if (tid < 384) hc[tid] = h0[b * NE + (tid - 256)];
    __syncthreads();

    if (tid < NE) {
        float acc = Qb[tid];
        const float* qr = Qw + tid * 384;
#pragma unroll 4
        for (int k = 0; k < 384; k += 4) {
            float4 w4 = *(const float4*)(qr + k);
            float4 x4 = *(const float4*)(hc + k);
            acc += w4.x * x4.x + w4.y * x4.y + w4.z * x4.z + w4.w * x4.w;
        }
        qv[tid] = acc;
    }
    __syncthreads();

    for (int idx = tid; idx < NH * NE; idx += 512) {
        int hh = idx >> 7, d = idx & 127;
        float acc = 0.f;
#pragma unroll
        for (int e = 0; e < EH; ++e)
            acc += qv[hh * EH + e] * Vw[(hh * EH + e) * NE + d];
        wdot[idx] = acc;
    }
    if (tid < NH) {
        float acc = 0.f;
#pragma unroll
        for (int e = 0; e < EH; ++e) acc += qv[tid * EH + e] * Vb[tid * EH + e];
        d0q[tid] = acc * 0.25f;   // pre-divide by sqrt(eh)=4
    }
    __syncthreads();

    // ---------------- phase 1: flash pass over c (dot + online softmax + hbar) ----------------
    // software-pipelined: regs hold tile t+1's data while tile t computes
    float m = -3.0e38f, l = 0.f;
    float hb0 = 0.f, hb1 = 0.f, hb2 = 0.f, hb3 = 0.f;   // hbar[wid][4*hl..4*hl+3], half-wave copies

    float4 r0 = *(const float4*)(hb + tid * 4);
    float4 r1 = *(const float4*)(hb + 2048 + tid * 4);
    float4 r2 = *(const float4*)(hb + 4096 + tid * 4);
    float4 r3 = *(const float4*)(hb + 6144 + tid * 4);

    const int c0 = tid >> 5;           // (tid*4)/128
    const int dd = (tid & 31) * 4;

    for (int t = 0; t < NC / TILE; ++t) {
        __syncthreads();   // previous tile's compute done, safe to overwrite hs
        *(float4*)(hs + (c0)      * LSTRIDE + dd) = r0;
        *(float4*)(hs + (c0 + 16) * LSTRIDE + dd) = r1;
        *(float4*)(hs + (c0 + 32) * LSTRIDE + dd) = r2;
        *(float4*)(hs + (c0 + 48) * LSTRIDE + dd) = r3;
        __syncthreads();   // hs ready

        if (t < NC / TILE - 1) {       // prefetch next tile; lands during compute below
            const float* src = hb + (t + 1) * TILE * NE;
            r0 = *(const float4*)(src + tid * 4);
            r1 = *(const float4*)(src + 2048 + tid * 4);
            r2 = *(const float4*)(src + 4096 + tid * 4);
            r3 = *(const float4*)(src + 6144 + tid * 4);
        }

        // dot for c = lane, head = wid
        float acc = 0.f;
        const float* wrow = wdot + wid * NE;
        const float* hrow = hs + lane * LSTRIDE;
#pragma unroll 8
        for (int dq = 0; dq < NE; dq += 4) {
            float4 w4 = *(const float4*)(wrow + dq);
            float4 x4 = *(const float4*)(hrow + dq);
            acc += w4.x * x4.x + w4.y * x4.y + w4.z * x4.z + w4.w * x4.w;
        }
        int mk = mask[b * NC + t * TILE + lane];
        float dt = fmaf(acc, 0.25f, d0q[wid]) - (float)mk * INFV;

        float tmax = wredmax64(dt);
        float mnew = fmaxf(m, tmax);
        float p = __expf(dt - mnew);
        float ts = wredsum64(p);
        float scale = __expf(m - mnew);
        l = l * scale + ts;
        if (mnew > m) { hb0 *= scale; hb1 *= scale; hb2 *= scale; hb3 *= scale; }  // wave-uniform branch
        m = mnew;

        // hbar += p[c] * h[c][:], half-wave per row, p broadcast via readlane (SALU, no LDS)
        const float* hbase = hs + hi * LSTRIDE + hl * 4;
#pragma unroll
        for (int cc = 0; cc < 32; ++cc) {
            float4 x4 = *(const float4*)(hbase + 2 * cc * LSTRIDE);
            float p0 = __uint_as_float(__builtin_amdgcn_readlane(__float_as_uint(p), 2 * cc));
            float p1 = __uint_as_float(__builtin_amdgcn_readlane(__float_as_uint(p), 2 * cc + 1));
            float pv = hi ? p1 : p0;
            hb0 = fmaf(x4.x, pv, hb0);
            hb1 = fmaf(x4.y, pv, hb1);
            hb2 = fmaf(x4.z, pv, hb2);
            hb3 = fmaf(x4.w, pv, hb3);
        }
    }
    // merge half-wave copies, normalize, publish
    hb0 += __shfl_xor(hb0, 32, 64);
    hb1 += __shfl_xor(hb1, 32, 64);
    hb2 += __shfl_xor(hb2, 32, 64);
    hb3 += __shfl_xor(hb3, 32, 64);
    float rl = 1.0f / l;
    if (lane < 32)
        *(float4*)(hbarn + wid * NE + hl * 4) = make_float4(hb0 * rl, hb1 * rl, hb2 * rl, hb3 * rl);
    __syncthreads();

    // ---------------- phase 2: context -> dec_out -> qf -> qk, qb0 ----------------
    if (tid < NE) {
        int hh = tid >> 4;
        float acc = Vb[tid];
        const float* vr = Vw + tid * NE;
        const float* hr = hbarn + hh * NE;
#pragma unroll 4
        for (int d = 0; d < NE; d += 4) {
            float4 w4 = *(const float4*)(vr + d);
            float4 x4 = *(const float4*)(hr + d);
            acc += w4.x * x4.x + w4.y * x4.y + w4.z * x4.z + w4.w * x4.w;
        }
        ctx[tid] = acc;
    }
    __syncthreads();
    if (tid < NE) {
        float acc = Wob[tid];
        const float* wr = Wow + tid * NE;
#pragma unroll 4
        for (int d = 0; d < NE; d += 4) {
            float4 w4 = *(const float4*)(wr + d);
            float4 x4 = *(const float4*)(ctx + d);
            acc += w4.x * x4.x + w4.y * x4.y + w4.z * x4.z + w4.w * x4.w;
        }
        dec[tid] = acc;
    }
    __syncthreads();
    if (tid < NE) {
        float acc = Qfb[tid];
        const float* wr = Qfw + tid * NE;
#pragma unroll 4
        for (int d = 0; d < NE; d += 4) {
            float4 w4 = *(const float4*)(wr + d);
            float4 x4 = *(const float4*)(dec + d);
            acc += w4.x * x4.x + w4.y * x4.y + w4.z * x4.z + w4.w * x4.w;
        }
        qfv[tid] = acc;
    }
    __syncthreads();
    if (tid < NE) {
        float acc = 0.f;
#pragma unroll 4
        for (int i = 0; i < NE; ++i) acc += qfv[i] * Kfw[i * NE + tid];
        qk[tid] = acc;
        red[tid] = qfv[tid] * Kfb[tid];
    }
    __syncthreads();
    if (tid == 0) {
        float s = 0.f;
        for (int i = 0; i < NE; ++i) s += red[i];
        qb0s = s;
    }
    __syncthreads();

    // ---------------- phase 3: logits = 10*tanh((qk.h + qb0)/sqrt(128)) - mask*INF ----------------
    const float invsq = 0.0883883476483184f;  // 1/sqrt(128)
    float4 qk4 = *(const float4*)(qk + hl * 4);
    float qb0 = qb0s;
    for (int it = 0; it < 64; ++it) {
        int cpair = wid * 128 + it * 2;
        float4 x4 = *(const float4*)(hb + cpair * NE + lane * 4);  // lanes cover 2 rows, coalesced 1KB
        float pd = qk4.x * x4.x + qk4.y * x4.y + qk4.z * x4.z + qk4.w * x4.w;
#pragma unroll
        for (int mm = 16; mm >= 1; mm >>= 1) pd += __shfl_xor(pd, mm, 64);
        if (hl == 0) {
            int c = cpair + hi;
            float x = (pd + qb0) * invsq;
            float e2 = __expf(2.f * x);
            float th = 1.f - 2.f / (e2 + 1.f);   // NaN-safe tanh (inf -> 1)
            float mk = (float)mask[b * NC + c];
            out[(size_t)b * NC + c] = 10.f * th - mk * INFV;
        }
    }
}

extern "C" void kernel_launch(void* const* d_in, const int* in_sizes, int n_in,
                              void* d_out, int out_size, void* d_ws, size_t ws_size,
                              hipStream_t stream) {
    const float* h     = (const float*)d_in[0];
    const float* hN    = (const float*)d_in[1];
    const float* hprev = (const float*)d_in[2];
    const float* h0    = (const float*)d_in[3];
    const int*   mask  = (const int*)d_in[4];
    const float* Qw    = (const float*)d_in[5];
    const float* Qb    = (const float*)d_in[6];
    const float* Vw    = (const float*)d_in[7];
    const float* Vb    = (const float*)d_in[8];
    const float* Wow   = (const float*)d_in[9];
    const float* Wob   = (const float*)d_in[10];
    const float* Qfw   = (const float*)d_in[11];
    const float* Qfb   = (const float*)d_in[12];
    const float* Kfw   = (const float*)d_in[13];
    const float* Kfb   = (const float*)d_in[14];

    decoder_mha_fused<<<dim3(NB), dim3(512), 0, stream>>>(
        h, hN, hprev, h0, mask, Qw, Qb, Vw, Vb, Wow, Wob, Qfw, Qfb, Kfw, Kfb,
        (float*)d_out);
}